// Round 13
// baseline (15447.343 us; speedup 1.0000x reference)
//
#include <hip/hip_runtime.h>
#include <hip/hip_fp16.h>

#define Hh 2048
#define VV 256
#define SS 2048
#define TT 2048
#define NB 128
#define NT 512

typedef _Float16 h4 __attribute__((ext_vector_type(4)));
typedef _Float16 h2 __attribute__((ext_vector_type(2)));
typedef unsigned int u32x4 __attribute__((ext_vector_type(4)));
typedef unsigned short u16x4 __attribute__((ext_vector_type(4)));

#if defined(__has_builtin)
#if __has_builtin(__builtin_amdgcn_fdot2)
#define FDOT2(a, b, c) __builtin_amdgcn_fdot2((a), (b), (c), false)
#endif
#endif
#ifndef FDOT2
#define FDOT2(a, b, c) \
  fmaf((float)(a).x, (float)(b).x, fmaf((float)(a).y, (float)(b).y, (c)))
#endif

#define SH(v, a, b) __builtin_shufflevector((v), (v), (a), (b))

// ---------------------------------------------------------------------------
// Generic NT GEMM: C[M][N] = A[M,K] . B[N,K]^T (+ biasM[m]) (+ biasN[n])
// ---------------------------------------------------------------------------
__global__ __launch_bounds__(256) void gemm_nt(const float* __restrict__ A,
                                               const float* __restrict__ B,
                                               const float* __restrict__ biasM,
                                               const float* __restrict__ biasN,
                                               float* __restrict__ C,
                                               int M, int N, int K) {
  __shared__ __align__(16) float At[32][68];
  __shared__ __align__(16) float Bt[32][68];
  const int t = threadIdx.x;
  const int m0 = blockIdx.x << 6, n0 = blockIdx.y << 6;
  const int r0 = t >> 3, c4 = (t & 7) << 2;
  const int tm = (t >> 4) << 2, tn = (t & 15) << 2;
  float acc[4][4];
#pragma unroll
  for (int i = 0; i < 4; ++i)
#pragma unroll
    for (int j = 0; j < 4; ++j) acc[i][j] = 0.f;

  for (int k0 = 0; k0 < K; k0 += 32) {
    float4 a0 = *(const float4*)&A[(size_t)(m0 + r0) * K + k0 + c4];
    float4 a1 = *(const float4*)&A[(size_t)(m0 + r0 + 32) * K + k0 + c4];
    float4 b0 = *(const float4*)&B[(size_t)(n0 + r0) * K + k0 + c4];
    float4 b1 = *(const float4*)&B[(size_t)(n0 + r0 + 32) * K + k0 + c4];
    __syncthreads();
    At[c4 + 0][r0] = a0.x; At[c4 + 1][r0] = a0.y; At[c4 + 2][r0] = a0.z; At[c4 + 3][r0] = a0.w;
    At[c4 + 0][r0 + 32] = a1.x; At[c4 + 1][r0 + 32] = a1.y; At[c4 + 2][r0 + 32] = a1.z; At[c4 + 3][r0 + 32] = a1.w;
    Bt[c4 + 0][r0] = b0.x; Bt[c4 + 1][r0] = b0.y; Bt[c4 + 2][r0] = b0.z; Bt[c4 + 3][r0] = b0.w;
    Bt[c4 + 0][r0 + 32] = b1.x; Bt[c4 + 1][r0 + 32] = b1.y; Bt[c4 + 2][r0 + 32] = b1.z; Bt[c4 + 3][r0 + 32] = b1.w;
    __syncthreads();
#pragma unroll
    for (int k = 0; k < 32; ++k) {
      float4 av = *(const float4*)&At[k][tm];
      float4 bv = *(const float4*)&Bt[k][tn];
      acc[0][0] = fmaf(av.x, bv.x, acc[0][0]);
      acc[0][1] = fmaf(av.x, bv.y, acc[0][1]);
      acc[0][2] = fmaf(av.x, bv.z, acc[0][2]);
      acc[0][3] = fmaf(av.x, bv.w, acc[0][3]);
      acc[1][0] = fmaf(av.y, bv.x, acc[1][0]);
      acc[1][1] = fmaf(av.y, bv.y, acc[1][1]);
      acc[1][2] = fmaf(av.y, bv.z, acc[1][2]);
      acc[1][3] = fmaf(av.y, bv.w, acc[1][3]);
      acc[2][0] = fmaf(av.z, bv.x, acc[2][0]);
      acc[2][1] = fmaf(av.z, bv.y, acc[2][1]);
      acc[2][2] = fmaf(av.z, bv.z, acc[2][2]);
      acc[2][3] = fmaf(av.z, bv.w, acc[2][3]);
      acc[3][0] = fmaf(av.w, bv.x, acc[3][0]);
      acc[3][1] = fmaf(av.w, bv.y, acc[3][1]);
      acc[3][2] = fmaf(av.w, bv.z, acc[3][2]);
      acc[3][3] = fmaf(av.w, bv.w, acc[3][3]);
    }
  }
#pragma unroll
  for (int i = 0; i < 4; ++i) {
    float bm = biasM ? biasM[m0 + tm + i] : 0.f;
#pragma unroll
    for (int j = 0; j < 4; ++j) {
      float bn = biasN ? biasN[n0 + tn + j] : 0.f;
      C[(size_t)(m0 + tm + i) * N + n0 + tn + j] = acc[i][j] + bm + bn;
    }
  }
}

// ---------------------------------------------------------------------------
// Persistent recurrence kernel — R7 tagged-dataflow (NB=128 x NT=512, the
// 13-round verified optimum) + PROVABLY-EXACT decoder limit-cycle early exit.
//
// hb: uint32[2][2048]; slot = (16-bit field << 16 | fp16 h bits), where the
// field = epoch tag (15 bits, <=4098) | stability bit (bit 15). Reader of
// step s polls buffer s&1 for tag s+1 on the LOW 15 tag bits. Producer at
// step s publishes tag s+2 | (stable<<15), stable := bits(hnew(s)) ==
// bits(hnew(s-2)) for its row (fp32 bitwise).
//
// Early exit: the decoder iterates a FIXED map (every step >= SS+1 uses the
// same token targets[1] — faithful to the reference's bug). If the global
// AND of stability bits for transition s-1 (>= SS+1) is true, then
// h(s) == h(s-2) bitwise for ALL 2048 rows; with constant input and
// deterministic fp32 arithmetic the trajectory is EXACTLY period-2 forever.
// Every block reads all 2048 slots each step, so every block computes the
// identical verdict at the identical step -> all blocks fill the remaining
// dec_hs rows with the two phase values (A = hnew(s-2) = would-be hnew(s),
// B = hnew(s-1)) and exit together (no publish needed; no deadlock). Filled
// values are bitwise what continued iteration would produce -> zero added
// error. If no limit cycle locks within the sequence, the bit never sets
// and the kernel runs exactly like R7/R12 (overhead ~1%).
//
// Block-wide AND without extra barriers: stab[4][8] per-wave cells with
// 4-slot rotation. Writers of slot s&3 (wave lane 0, pre-barrier step s) and
// the reset of slot (s+2)&3 (threads t<8, pre-barrier step s) are separated
// from that slot's readers (post-barrier step s-2) and prior writers by >=1
// __syncthreads in every pairing -> race-free.
//
// Buffer-reuse safety: unchanged transitive chain — a producer writes epoch
// e+2 only after polling ALL of e+1, which requires every block to have
// fully read epoch e. Stale graph-replay words carry identical bits (same
// inputs, deterministic) -> benign early reads, as before.
// ---------------------------------------------------------------------------
__global__ __launch_bounds__(NT) void recur_kernel(
    const float* __restrict__ giT_enc, const float* __restrict__ giT_dec,
    const float* __restrict__ enc_w_hh, const float* __restrict__ enc_b_hh,
    const float* __restrict__ dec_w_hh, const float* __restrict__ dec_b_hh,
    const int* __restrict__ inputs, const int* __restrict__ targets,
    unsigned int* __restrict__ hb, float* __restrict__ dec_hs) {
  __shared__ __align__(16) float gi_lds[48 * VV];       // 48 KB
  __shared__ __align__(16) _Float16 h16[2][Hh];         // 8 KB (double buffer)
  __shared__ __align__(16) unsigned short tok_lds[SS];  // 4 KB
  __shared__ float gidec_lds[96];
  __shared__ int stab[4][8];      // 4-slot-rotation per-wave stability vote
  __shared__ float fillA[16], fillB[16];  // limit-cycle phase values

  const int t = threadIdx.x;
  const int b = blockIdx.x;
  const int bks = b << 4;  // 16 rows per block
  const int w = t >> 6, l = t & 63;
  const int ri = (w << 1) + (l & 1);  // this lane's epilogue row (in-block)

  // ---- recurrent weights + biases: two rows per wave, all in registers
  h4 wregA[24], wregB[24];
  float br_, bz_, bn_;
  auto load_wb = [&](const float* W, const float* B) {
#pragma unroll
    for (int g = 0; g < 3; ++g) {
      const float* r0 = W + ((size_t)(g * Hh + bks + (w << 1) + 0)) * Hh + (l << 2);
      const float* r1 = W + ((size_t)(g * Hh + bks + (w << 1) + 1)) * Hh + (l << 2);
#pragma unroll
      for (int q = 0; q < 8; ++q) {
        float4 v0 = *(const float4*)&r0[q * 256];
        float4 v1 = *(const float4*)&r1[q * 256];
        wregA[g * 8 + q] = h4{(_Float16)v0.x, (_Float16)v0.y,
                             (_Float16)v0.z, (_Float16)v0.w};
        wregB[g * 8 + q] = h4{(_Float16)v1.x, (_Float16)v1.y,
                             (_Float16)v1.z, (_Float16)v1.w};
      }
    }
    br_ = B[bks + ri];
    bz_ = B[Hh + bks + ri];
    bn_ = B[2 * Hh + bks + ri];
  };
  load_wb(enc_w_hh, enc_b_hh);

  // ---- stage encoder per-vocab input-gate slice: gi_lds[(g*16+rr)*256 + v]
  for (int r = 0; r < 48; ++r) {
    const int g = r >> 4, rr = r & 15;
    const float4* src = (const float4*)(giT_enc + ((size_t)(g * Hh + bks + rr)) * VV);
    if (t < 64) ((float4*)&gi_lds[r * VV])[t] = src[t];
  }

  // ---- tokens
  for (int u = t; u < SS; u += NT) tok_lds[u] = (unsigned short)inputs[u];

  // ---- decoder input-gates: only tokens {0, targets[1]}
  if (t < 96) {
    const int sel = t / 48, r48 = t % 48;
    const int tk = sel ? targets[1] : 0;
    const int g = r48 >> 4, rr = r48 & 15;
    gidec_lds[sel * 48 + r48] = giT_dec[((size_t)(g * Hh + bks + rr)) * VV + tk];
  }

  if (t < 32) stab[t >> 3][t & 7] = 1;  // benign init race near step 0 only

  // ---- init own h slots: fp16 0.0 (bits 0), tag 1 (buffer 0)
  if (t < 16) {
    __hip_atomic_store(&hb[bks + t], 0x00010000u, __ATOMIC_RELAXED,
                       __HIP_MEMORY_SCOPE_AGENT);
  }
  float hprev = 0.0f;   // lanes 0/1 of wave w: running fp32 h[bks+2w+l]
  float hprev2 = 0.0f;  // value two steps back (period-2 detection)

  for (int step = 0; step < SS + TT; ++step) {
    if (step == SS) load_wb(dec_w_hh, dec_b_hh);  // private regs: no hazard
    const int sb = step & 1;

    // ---- poll the 4 tagged slots this thread stages; collect stability bits
    unsigned int mybit;
    {
      const unsigned int* addr = hb + ((size_t)sb << 11) + (t << 2);
      const unsigned int want = ((unsigned int)(step + 1)) << 16;
      u32x4 v;
      for (;;) {
        asm volatile(
            "global_load_dwordx4 %0, %1, off sc0 sc1\n\t"
            "s_waitcnt vmcnt(0)"
            : "=&v"(v)
            : "v"(addr)
            : "memory");
        if ((((v.x ^ want) | (v.y ^ want) | (v.z ^ want) | (v.w ^ want)) &
             0x7FFF0000u) == 0u)
          break;
        __builtin_amdgcn_s_sleep(1);
      }
      mybit = (v.x & v.y & v.z & v.w) >> 31;  // AND of 4 stability bits
      u16x4 hu = {(unsigned short)v.x, (unsigned short)v.y,
                  (unsigned short)v.z, (unsigned short)v.w};
      *(u16x4*)&h16[sb][t << 2] = hu;
    }
    // wave-level AND of bits; lane 0 records the wave's vote (slot step&3);
    // threads t<8 reset slot (step+2)&3 for its reuse two steps from now.
    {
      const int wv = __all((int)mybit);
      if (l == 0) stab[step & 3][w] = wv;
      if (t < 8) stab[(step + 2) & 3][t] = 1;
    }
    __syncthreads();

    // ---- global period-2 lock check (decoder constant-input region only)
    if (step >= SS + 2) {
      const int g = stab[step & 3][0] & stab[step & 3][1] & stab[step & 3][2] &
                    stab[step & 3][3] & stab[step & 3][4] & stab[step & 3][5] &
                    stab[step & 3][6] & stab[step & 3][7];
      if (g) {
        // h(step) == h(step-2) bitwise globally -> exact period-2 forever.
        // Would-be hnew(step) = hprev2 (phase A); hnew(step+1) = hprev (B).
        if (l < 2) { fillA[ri] = hprev2; fillB[ri] = hprev; }
        __syncthreads();
        const int j0 = step - SS;
        const int total = (TT - j0) << 4;
        for (int idx = t; idx < total; idx += NT) {
          const int jj = j0 + (idx >> 4), col = idx & 15;
          dec_hs[(size_t)jj * Hh + bks + col] =
              ((jj - j0) & 1) ? fillB[col] : fillA[col];
        }
        return;  // all blocks take this path at the same step
      }
    }

    // ---- six gate-row dot products (2 rows x 3 gates), fp16 dot2, fp32 acc
    float arA = 0.f, azA = 0.f, anA = 0.f;
    float arB = 0.f, azB = 0.f, anB = 0.f;
#pragma unroll
    for (int q = 0; q < 8; ++q) {
      const int c = q * 256 + (l << 2);
      h4 hv = *(const h4*)&h16[sb][c];
      h2 hlo = SH(hv, 0, 1);
      h2 hhi = SH(hv, 2, 3);
      h4 a_r = wregA[q], a_z = wregA[8 + q], a_n = wregA[16 + q];
      h4 b_r = wregB[q], b_z = wregB[8 + q], b_n = wregB[16 + q];
      arA = FDOT2(SH(a_r, 0, 1), hlo, arA); arA = FDOT2(SH(a_r, 2, 3), hhi, arA);
      azA = FDOT2(SH(a_z, 0, 1), hlo, azA); azA = FDOT2(SH(a_z, 2, 3), hhi, azA);
      anA = FDOT2(SH(a_n, 0, 1), hlo, anA); anA = FDOT2(SH(a_n, 2, 3), hhi, anA);
      arB = FDOT2(SH(b_r, 0, 1), hlo, arB); arB = FDOT2(SH(b_r, 2, 3), hhi, arB);
      azB = FDOT2(SH(b_z, 0, 1), hlo, azB); azB = FDOT2(SH(b_z, 2, 3), hhi, azB);
      anB = FDOT2(SH(b_n, 0, 1), hlo, anB); anB = FDOT2(SH(b_n, 2, 3), hhi, anB);
    }

    // ---- gate inputs hoisted above the reduce (row-matched via ri)
    float gr, gz, gn;
    if (step < SS) {
      const int tk = tok_lds[step];
      gr = gi_lds[(0 + ri) * VV + tk];
      gz = gi_lds[(16 + ri) * VV + tk];
      gn = gi_lds[(32 + ri) * VV + tk];
    } else {
      const int sel = (step == SS) ? 0 : 48;
      gr = gidec_lds[sel + 0 + ri];
      gz = gidec_lds[sel + 16 + ri];
      gn = gidec_lds[sel + 32 + ri];
    }

#pragma unroll
    for (int off = 32; off > 0; off >>= 1) {
      arA += __shfl_xor(arA, off); azA += __shfl_xor(azA, off); anA += __shfl_xor(anA, off);
      arB += __shfl_xor(arB, off); azB += __shfl_xor(azB, off); anB += __shfl_xor(anB, off);
    }

    if (l < 2) {  // lane 0 -> row bks+2w, lane 1 -> row bks+2w+1
      const float ar = l ? arB : arA;
      const float az = l ? azB : azA;
      const float an = l ? anB : anA;
      const float xr = gr + ar + br_;
      const float xz = gz + az + bz_;
      const float hn = an + bn_;
      const float rr = 1.f / (1.f + __expf(-xr));
      const float zz = 1.f / (1.f + __expf(-xz));
      const float nn = tanhf(gn + rr * hn);
      const float hnew = (1.f - zz) * nn + zz * hprev;

      const unsigned int stable =
          (__float_as_uint(hnew) == __float_as_uint(hprev2)) ? 0x8000u : 0u;
      _Float16 hf = (_Float16)hnew;
      const unsigned int pk =
          ((((unsigned int)(step + 2)) | stable) << 16) |
          (unsigned int)__builtin_bit_cast(unsigned short, hf);
      __hip_atomic_store(&hb[(((size_t)((step + 1) & 1)) << 11) + bks + ri], pk,
                         __ATOMIC_RELAXED, __HIP_MEMORY_SCOPE_AGENT);
      if (step >= SS) dec_hs[(size_t)(step - SS) * Hh + bks + ri] = hnew;
      hprev2 = hprev;
      hprev = hnew;
    }
    // no trailing barrier: h16 is double-buffered; weights/biases are private
  }
}

// ---------------------------------------------------------------------------
extern "C" void kernel_launch(void* const* d_in, const int* in_sizes, int n_in,
                              void* d_out, int out_size, void* d_ws, size_t ws_size,
                              hipStream_t stream) {
  (void)in_sizes; (void)n_in; (void)out_size; (void)ws_size;
  const int* inputs = (const int*)d_in[0];
  const int* targets = (const int*)d_in[1];
  const float* emb = (const float*)d_in[2];
  const float* enc_w_ih = (const float*)d_in[3];
  const float* enc_w_hh = (const float*)d_in[4];
  const float* enc_b_ih = (const float*)d_in[5];
  const float* enc_b_hh = (const float*)d_in[6];
  const float* dec_w_ih = (const float*)d_in[7];
  const float* dec_w_hh = (const float*)d_in[8];
  const float* dec_b_ih = (const float*)d_in[9];
  const float* dec_b_hh = (const float*)d_in[10];
  const float* fc_w = (const float*)d_in[11];
  const float* fc_b = (const float*)d_in[12];
  float* out = (float*)d_out;

  // workspace layout
  float* giT_enc = (float*)d_ws;                          // [6144][256]
  float* giT_dec = giT_enc + (size_t)6144 * 256;          // [6144][256]
  float* dec_hs = giT_dec + (size_t)6144 * 256;           // [2048][2048]
  unsigned int* hb =
      (unsigned int*)(dec_hs + (size_t)TT * Hh);          // [2][2048] tagged u32

  // per-vocab input-gate tables: giT[r][v] = W_ih[r] . emb[v] + b_ih[r]
  gemm_nt<<<dim3(96, 4), 256, 0, stream>>>(enc_w_ih, emb, enc_b_ih, nullptr,
                                           giT_enc, 3 * Hh, VV, Hh);
  gemm_nt<<<dim3(96, 4), 256, 0, stream>>>(dec_w_ih, emb, dec_b_ih, nullptr,
                                           giT_dec, 3 * Hh, VV, Hh);

  void* args[] = {&giT_enc, &giT_dec, &enc_w_hh, &enc_b_hh, &dec_w_hh,
                  &dec_b_hh, &inputs, &targets, &hb, &dec_hs};
  hipError_t e = hipLaunchCooperativeKernel((void*)recur_kernel, dim3(NB),
                                            dim3(NT), args, 0, stream);
  if (e != hipSuccess) {
    recur_kernel<<<dim3(NB), dim3(NT), 0, stream>>>(
        giT_enc, giT_dec, enc_w_hh, enc_b_hh, dec_w_hh, dec_b_hh, inputs,
        targets, hb, dec_hs);
  }

  // out[t][v] = dec_hs[t] . fc_w[v] + fc_b[v]
  gemm_nt<<<dim3(32, 4), 256, 0, stream>>>(dec_hs, fc_w, nullptr, fc_b, out,
                                           TT, VV, Hh);
}

// Round 14
// 14989.925 us; speedup vs baseline: 1.0305x; 1.0305x over previous
//
#include <hip/hip_runtime.h>
#include <hip/hip_fp16.h>

#define Hh 2048
#define VV 256
#define SS 2048
#define TT 2048
#define NB 128
#define NT 512

typedef _Float16 h4 __attribute__((ext_vector_type(4)));
typedef _Float16 h2 __attribute__((ext_vector_type(2)));
typedef unsigned int u32x4 __attribute__((ext_vector_type(4)));
typedef unsigned short u16x4 __attribute__((ext_vector_type(4)));

#if defined(__has_builtin)
#if __has_builtin(__builtin_amdgcn_fdot2)
#define FDOT2(a, b, c) __builtin_amdgcn_fdot2((a), (b), (c), false)
#endif
#endif
#ifndef FDOT2
#define FDOT2(a, b, c) \
  fmaf((float)(a).x, (float)(b).x, fmaf((float)(a).y, (float)(b).y, (c)))
#endif

#define SH(v, a, b) __builtin_shufflevector((v), (v), (a), (b))

// ---------------------------------------------------------------------------
// Generic NT GEMM: C[M][N] = A[M,K] . B[N,K]^T (+ biasM[m]) (+ biasN[n])
// ---------------------------------------------------------------------------
__global__ __launch_bounds__(256) void gemm_nt(const float* __restrict__ A,
                                               const float* __restrict__ B,
                                               const float* __restrict__ biasM,
                                               const float* __restrict__ biasN,
                                               float* __restrict__ C,
                                               int M, int N, int K) {
  __shared__ __align__(16) float At[32][68];
  __shared__ __align__(16) float Bt[32][68];
  const int t = threadIdx.x;
  const int m0 = blockIdx.x << 6, n0 = blockIdx.y << 6;
  const int r0 = t >> 3, c4 = (t & 7) << 2;
  const int tm = (t >> 4) << 2, tn = (t & 15) << 2;
  float acc[4][4];
#pragma unroll
  for (int i = 0; i < 4; ++i)
#pragma unroll
    for (int j = 0; j < 4; ++j) acc[i][j] = 0.f;

  for (int k0 = 0; k0 < K; k0 += 32) {
    float4 a0 = *(const float4*)&A[(size_t)(m0 + r0) * K + k0 + c4];
    float4 a1 = *(const float4*)&A[(size_t)(m0 + r0 + 32) * K + k0 + c4];
    float4 b0 = *(const float4*)&B[(size_t)(n0 + r0) * K + k0 + c4];
    float4 b1 = *(const float4*)&B[(size_t)(n0 + r0 + 32) * K + k0 + c4];
    __syncthreads();
    At[c4 + 0][r0] = a0.x; At[c4 + 1][r0] = a0.y; At[c4 + 2][r0] = a0.z; At[c4 + 3][r0] = a0.w;
    At[c4 + 0][r0 + 32] = a1.x; At[c4 + 1][r0 + 32] = a1.y; At[c4 + 2][r0 + 32] = a1.z; At[c4 + 3][r0 + 32] = a1.w;
    Bt[c4 + 0][r0] = b0.x; Bt[c4 + 1][r0] = b0.y; Bt[c4 + 2][r0] = b0.z; Bt[c4 + 3][r0] = b0.w;
    Bt[c4 + 0][r0 + 32] = b1.x; Bt[c4 + 1][r0 + 32] = b1.y; Bt[c4 + 2][r0 + 32] = b1.z; Bt[c4 + 3][r0 + 32] = b1.w;
    __syncthreads();
#pragma unroll
    for (int k = 0; k < 32; ++k) {
      float4 av = *(const float4*)&At[k][tm];
      float4 bv = *(const float4*)&Bt[k][tn];
      acc[0][0] = fmaf(av.x, bv.x, acc[0][0]);
      acc[0][1] = fmaf(av.x, bv.y, acc[0][1]);
      acc[0][2] = fmaf(av.x, bv.z, acc[0][2]);
      acc[0][3] = fmaf(av.x, bv.w, acc[0][3]);
      acc[1][0] = fmaf(av.y, bv.x, acc[1][0]);
      acc[1][1] = fmaf(av.y, bv.y, acc[1][1]);
      acc[1][2] = fmaf(av.y, bv.z, acc[1][2]);
      acc[1][3] = fmaf(av.y, bv.w, acc[1][3]);
      acc[2][0] = fmaf(av.z, bv.x, acc[2][0]);
      acc[2][1] = fmaf(av.z, bv.y, acc[2][1]);
      acc[2][2] = fmaf(av.z, bv.z, acc[2][2]);
      acc[2][3] = fmaf(av.z, bv.w, acc[2][3]);
      acc[3][0] = fmaf(av.w, bv.x, acc[3][0]);
      acc[3][1] = fmaf(av.w, bv.y, acc[3][1]);
      acc[3][2] = fmaf(av.w, bv.z, acc[3][2]);
      acc[3][3] = fmaf(av.w, bv.w, acc[3][3]);
    }
  }
#pragma unroll
  for (int i = 0; i < 4; ++i) {
    float bm = biasM ? biasM[m0 + tm + i] : 0.f;
#pragma unroll
    for (int j = 0; j < 4; ++j) {
      float bn = biasN ? biasN[n0 + tn + j] : 0.f;
      C[(size_t)(m0 + tm + i) * N + n0 + tn + j] = acc[i][j] + bm + bn;
    }
  }
}

// ---------------------------------------------------------------------------
// Persistent recurrence kernel — R7 tagged-dataflow (NB=128 x NT=512, the
// verified optimum) + EXACT fp16-broadcast lock early exit.
//
// hb: uint32[2][2048]; slot = (16-bit field << 16 | fp16 h bits); field =
// epoch tag (15 bits, <=4098) | vote bit (bit 15). Reader of step s polls
// buffer s&1 for tag s+1 on the low 15 bits; producer at step s publishes
// tag s+2 (+ vote). Relaxed agent stores; R1 transitive safety chain intact.
//
// Early exit (exact): decoder steps >= SS+1 iterate a fixed map whose gate
// dots depend ONLY on the fp16 BROADCAST h16 (and constant gidec). R13
// proved the fp32 state never locks bitwise (ulp wander); the fp16 broadcast
// is 2^13 coarser. If h16(s) == h16(s-1) (L-lock, computed IDENTICALLY by
// every block from its own staged registers), gates are constant and each
// row obeys h <- fmaf(zz, h, (1-zz)*nn) with constant coefficients. At
// L-locked steps with step%64==0, each row-owner forward-simulates its own
// affine tail verifying fp16(h_k) stays == the locked value through the end
// (if so, the broadcast provably never changes again -> the affine tail IS
// the exact continued computation). The per-row verdict rides the publish
// vote bit; next step's regular poll gives every block the same global AND;
// on fire, owners fill their remaining dec_hs rows from the local affine
// iteration (same fmaf expression -> bitwise-exact) and ALL blocks return
// together (no further epochs needed -> no deadlock). Main-loop update and
// fill both use hnew = fmaf(zz, hprev, (1-zz)*nn) so the two code sites are
// bitwise-identical regardless of compiler contraction.
//
// Null-safe: if the broadcast never locks, overhead is a register compare +
// vote per step and rare bounded sims (~3.4us per 64 steps while L holds).
// ---------------------------------------------------------------------------
__global__ __launch_bounds__(NT) void recur_kernel(
    const float* __restrict__ giT_enc, const float* __restrict__ giT_dec,
    const float* __restrict__ enc_w_hh, const float* __restrict__ enc_b_hh,
    const float* __restrict__ dec_w_hh, const float* __restrict__ dec_b_hh,
    const int* __restrict__ inputs, const int* __restrict__ targets,
    unsigned int* __restrict__ hb, float* __restrict__ dec_hs) {
  __shared__ __align__(16) float gi_lds[48 * VV];       // 48 KB
  __shared__ __align__(16) _Float16 h16[2][Hh];         // 8 KB (double buffer)
  __shared__ __align__(16) unsigned short tok_lds[SS];  // 4 KB
  __shared__ float gidec_lds[96];
  __shared__ int stab[4][8];  // per-wave {fireAND, L} votes, 4-slot rotation

  const int t = threadIdx.x;
  const int b = blockIdx.x;
  const int bks = b << 4;  // 16 rows per block
  const int w = t >> 6, l = t & 63;
  const int ri = (w << 1) + (l & 1);  // this lane's epilogue row (in-block)

  // ---- recurrent weights + biases: two rows per wave, all in registers
  h4 wregA[24], wregB[24];
  float br_, bz_, bn_;
  auto load_wb = [&](const float* W, const float* B) {
#pragma unroll
    for (int g = 0; g < 3; ++g) {
      const float* r0 = W + ((size_t)(g * Hh + bks + (w << 1) + 0)) * Hh + (l << 2);
      const float* r1 = W + ((size_t)(g * Hh + bks + (w << 1) + 1)) * Hh + (l << 2);
#pragma unroll
      for (int q = 0; q < 8; ++q) {
        float4 v0 = *(const float4*)&r0[q * 256];
        float4 v1 = *(const float4*)&r1[q * 256];
        wregA[g * 8 + q] = h4{(_Float16)v0.x, (_Float16)v0.y,
                             (_Float16)v0.z, (_Float16)v0.w};
        wregB[g * 8 + q] = h4{(_Float16)v1.x, (_Float16)v1.y,
                             (_Float16)v1.z, (_Float16)v1.w};
      }
    }
    br_ = B[bks + ri];
    bz_ = B[Hh + bks + ri];
    bn_ = B[2 * Hh + bks + ri];
  };
  load_wb(enc_w_hh, enc_b_hh);

  // ---- stage encoder per-vocab input-gate slice: gi_lds[(g*16+rr)*256 + v]
  for (int r = 0; r < 48; ++r) {
    const int g = r >> 4, rr = r & 15;
    const float4* src = (const float4*)(giT_enc + ((size_t)(g * Hh + bks + rr)) * VV);
    if (t < 64) ((float4*)&gi_lds[r * VV])[t] = src[t];
  }

  // ---- tokens
  for (int u = t; u < SS; u += NT) tok_lds[u] = (unsigned short)inputs[u];

  // ---- decoder input-gates: only tokens {0, targets[1]}
  if (t < 96) {
    const int sel = t / 48, r48 = t % 48;
    const int tk = sel ? targets[1] : 0;
    const int g = r48 >> 4, rr = r48 & 15;
    gidec_lds[sel * 48 + r48] = giT_dec[((size_t)(g * Hh + bks + rr)) * VV + tk];
  }

  if (t < 32) stab[t >> 3][t & 7] = 0;

  // ---- init own h slots: fp16 0.0 (bits 0), tag 1 (buffer 0)
  if (t < 16) {
    __hip_atomic_store(&hb[bks + t], 0x00010000u, __ATOMIC_RELAXED,
                       __HIP_MEMORY_SCOPE_AGENT);
  }
  float hprev = 0.0f;  // lanes 0/1 of wave w: running fp32 h[bks+2w+l]
  float czz = 0.0f, cfc = 0.0f;  // saved affine coefficients (owners)
  unsigned long long prevpack = 0xFFFFFFFFFFFFFFFFull;  // impossible value

  for (int step = 0; step < SS + TT; ++step) {
    if (step == SS) load_wb(dec_w_hh, dec_b_hh);  // private regs: no hazard
    const int sb = step & 1;

    // ---- poll the 4 tagged slots this thread stages (one dwordx4)
    unsigned int mybit;
    int leq;
    {
      const unsigned int* addr = hb + ((size_t)sb << 11) + (t << 2);
      const unsigned int want = ((unsigned int)(step + 1)) << 16;
      u32x4 v;
      for (;;) {
        asm volatile(
            "global_load_dwordx4 %0, %1, off sc0 sc1\n\t"
            "s_waitcnt vmcnt(0)"
            : "=&v"(v)
            : "v"(addr)
            : "memory");
        if ((((v.x ^ want) | (v.y ^ want) | (v.z ^ want) | (v.w ^ want)) &
             0x7FFF0000u) == 0u)
          break;
        __builtin_amdgcn_s_sleep(1);
      }
      mybit = (v.x & v.y & v.z & v.w) >> 31;  // AND of 4 vote bits
      const unsigned long long curpack =
          (unsigned long long)((v.x & 0xFFFFu) | (v.y << 16)) |
          ((unsigned long long)((v.z & 0xFFFFu) | (v.w << 16)) << 32);
      leq = (curpack == prevpack);  // my 4 slots unchanged vs last step
      prevpack = curpack;
      u16x4 hu = {(unsigned short)v.x, (unsigned short)v.y,
                  (unsigned short)v.z, (unsigned short)v.w};
      *(u16x4*)&h16[sb][t << 2] = hu;
    }
    {
      const int wv = (__all((int)mybit) << 1) | __all(leq);
      if (l == 0) stab[step & 3][w] = wv;
    }
    __syncthreads();

    // ---- global verdicts (identical in every block: same broadcast data)
    int evalL = 0;
    if (step >= SS + 2) {
      const int a = stab[step & 3][0] & stab[step & 3][1] & stab[step & 3][2] &
                    stab[step & 3][3] & stab[step & 3][4] & stab[step & 3][5] &
                    stab[step & 3][6] & stab[step & 3][7];
      if (a & 2) {
        // FIRE: every row verified its affine tail keeps the broadcast
        // locked -> remaining evolution is exactly the local affine map.
        if (l < 2) {
          float cur = hprev;  // h after step-1
          for (int j = step - SS; j < TT; ++j) {
            cur = fmaf(czz, cur, cfc);
            dec_hs[(size_t)j * Hh + bks + ri] = cur;
          }
        }
        return;  // all blocks fire at the same step
      }
      evalL = a & 1;
    }

    // ---- six gate-row dot products (2 rows x 3 gates), fp16 dot2, fp32 acc
    float arA = 0.f, azA = 0.f, anA = 0.f;
    float arB = 0.f, azB = 0.f, anB = 0.f;
#pragma unroll
    for (int q = 0; q < 8; ++q) {
      const int c = q * 256 + (l << 2);
      h4 hv = *(const h4*)&h16[sb][c];
      h2 hlo = SH(hv, 0, 1);
      h2 hhi = SH(hv, 2, 3);
      h4 a_r = wregA[q], a_z = wregA[8 + q], a_n = wregA[16 + q];
      h4 b_r = wregB[q], b_z = wregB[8 + q], b_n = wregB[16 + q];
      arA = FDOT2(SH(a_r, 0, 1), hlo, arA); arA = FDOT2(SH(a_r, 2, 3), hhi, arA);
      azA = FDOT2(SH(a_z, 0, 1), hlo, azA); azA = FDOT2(SH(a_z, 2, 3), hhi, azA);
      anA = FDOT2(SH(a_n, 0, 1), hlo, anA); anA = FDOT2(SH(a_n, 2, 3), hhi, anA);
      arB = FDOT2(SH(b_r, 0, 1), hlo, arB); arB = FDOT2(SH(b_r, 2, 3), hhi, arB);
      azB = FDOT2(SH(b_z, 0, 1), hlo, azB); azB = FDOT2(SH(b_z, 2, 3), hhi, azB);
      anB = FDOT2(SH(b_n, 0, 1), hlo, anB); anB = FDOT2(SH(b_n, 2, 3), hhi, anB);
    }

    // ---- gate inputs hoisted above the reduce (row-matched via ri)
    float gr, gz, gn;
    if (step < SS) {
      const int tk = tok_lds[step];
      gr = gi_lds[(0 + ri) * VV + tk];
      gz = gi_lds[(16 + ri) * VV + tk];
      gn = gi_lds[(32 + ri) * VV + tk];
    } else {
      const int sel = (step == SS) ? 0 : 48;
      gr = gidec_lds[sel + 0 + ri];
      gz = gidec_lds[sel + 16 + ri];
      gn = gidec_lds[sel + 32 + ri];
    }

#pragma unroll
    for (int off = 32; off > 0; off >>= 1) {
      arA += __shfl_xor(arA, off); azA += __shfl_xor(azA, off); anA += __shfl_xor(anA, off);
      arB += __shfl_xor(arB, off); azB += __shfl_xor(azB, off); anB += __shfl_xor(anB, off);
    }

    if (l < 2) {  // lane 0 -> row bks+2w, lane 1 -> row bks+2w+1
      const float ar = l ? arB : arA;
      const float az = l ? azB : azA;
      const float an = l ? anB : anA;
      const float xr = gr + ar + br_;
      const float xz = gz + az + bz_;
      const float hn = an + bn_;
      const float rr = 1.f / (1.f + __expf(-xr));
      const float zz = 1.f / (1.f + __expf(-xz));
      const float nn = tanhf(gn + rr * hn);
      const float cc1 = (1.f - zz) * nn;
      const float hnew = fmaf(zz, hprev, cc1);  // same expr as fill loop

      unsigned int vote = 0u;
      if (evalL && (step & 63) == 0) {
        // gates constant while broadcast locked; verify my row's affine
        // tail keeps its fp16 image at the locked value through the end.
        czz = zz; cfc = cc1;
        const unsigned short locked =
            __builtin_bit_cast(unsigned short, (_Float16)hprev);
        float cur = hnew;
        vote = 0x8000u;
        for (int k = step + 1; k < SS + TT; ++k) {
          _Float16 cf = (_Float16)cur;
          if (__builtin_bit_cast(unsigned short, cf) != locked) {
            vote = 0u;
            break;
          }
          cur = fmaf(czz, cur, cfc);
        }
      }

      _Float16 hf = (_Float16)hnew;
      const unsigned int pk =
          ((((unsigned int)(step + 2)) | vote) << 16) |
          (unsigned int)__builtin_bit_cast(unsigned short, hf);
      __hip_atomic_store(&hb[(((size_t)((step + 1) & 1)) << 11) + bks + ri], pk,
                         __ATOMIC_RELAXED, __HIP_MEMORY_SCOPE_AGENT);
      if (step >= SS) dec_hs[(size_t)(step - SS) * Hh + bks + ri] = hnew;
      hprev = hnew;
    }
    // no trailing barrier: h16 is double-buffered; weights/biases are private
  }
}

// ---------------------------------------------------------------------------
extern "C" void kernel_launch(void* const* d_in, const int* in_sizes, int n_in,
                              void* d_out, int out_size, void* d_ws, size_t ws_size,
                              hipStream_t stream) {
  (void)in_sizes; (void)n_in; (void)out_size; (void)ws_size;
  const int* inputs = (const int*)d_in[0];
  const int* targets = (const int*)d_in[1];
  const float* emb = (const float*)d_in[2];
  const float* enc_w_ih = (const float*)d_in[3];
  const float* enc_w_hh = (const float*)d_in[4];
  const float* enc_b_ih = (const float*)d_in[5];
  const float* enc_b_hh = (const float*)d_in[6];
  const float* dec_w_ih = (const float*)d_in[7];
  const float* dec_w_hh = (const float*)d_in[8];
  const float* dec_b_ih = (const float*)d_in[9];
  const float* dec_b_hh = (const float*)d_in[10];
  const float* fc_w = (const float*)d_in[11];
  const float* fc_b = (const float*)d_in[12];
  float* out = (float*)d_out;

  // workspace layout
  float* giT_enc = (float*)d_ws;                          // [6144][256]
  float* giT_dec = giT_enc + (size_t)6144 * 256;          // [6144][256]
  float* dec_hs = giT_dec + (size_t)6144 * 256;           // [2048][2048]
  unsigned int* hb =
      (unsigned int*)(dec_hs + (size_t)TT * Hh);          // [2][2048] tagged u32

  // per-vocab input-gate tables: giT[r][v] = W_ih[r] . emb[v] + b_ih[r]
  gemm_nt<<<dim3(96, 4), 256, 0, stream>>>(enc_w_ih, emb, enc_b_ih, nullptr,
                                           giT_enc, 3 * Hh, VV, Hh);
  gemm_nt<<<dim3(96, 4), 256, 0, stream>>>(dec_w_ih, emb, dec_b_ih, nullptr,
                                           giT_dec, 3 * Hh, VV, Hh);

  void* args[] = {&giT_enc, &giT_dec, &enc_w_hh, &enc_b_hh, &dec_w_hh,
                  &dec_b_hh, &inputs, &targets, &hb, &dec_hs};
  hipError_t e = hipLaunchCooperativeKernel((void*)recur_kernel, dim3(NB),
                                            dim3(NT), args, 0, stream);
  if (e != hipSuccess) {
    recur_kernel<<<dim3(NB), dim3(NT), 0, stream>>>(
        giT_enc, giT_dec, enc_w_hh, enc_b_hh, dec_w_hh, dec_b_hh, inputs,
        targets, hb, dec_hs);
  }

  // out[t][v] = dec_hs[t] . fc_w[v] + fc_b[v]
  gemm_nt<<<dim3(32, 4), 256, 0, stream>>>(dec_hs, fc_w, nullptr, fc_b, out,
                                           TT, VV, Hh);
}

// Round 15
// 14903.572 us; speedup vs baseline: 1.0365x; 1.0058x over previous
//
#include <hip/hip_runtime.h>
#include <hip/hip_fp16.h>

#define Hh 2048
#define VV 256
#define SS 2048
#define TT 2048
#define NB 128
#define NT 512

typedef _Float16 h4 __attribute__((ext_vector_type(4)));
typedef _Float16 h2 __attribute__((ext_vector_type(2)));
typedef unsigned int u32x4 __attribute__((ext_vector_type(4)));
typedef unsigned short u16x4 __attribute__((ext_vector_type(4)));

#if defined(__has_builtin)
#if __has_builtin(__builtin_amdgcn_fdot2)
#define FDOT2(a, b, c) __builtin_amdgcn_fdot2((a), (b), (c), false)
#endif
#endif
#ifndef FDOT2
#define FDOT2(a, b, c) \
  fmaf((float)(a).x, (float)(b).x, fmaf((float)(a).y, (float)(b).y, (c)))
#endif

#define SH(v, a, b) __builtin_shufflevector((v), (v), (a), (b))

// ---------------------------------------------------------------------------
// Generic NT GEMM: C[M][N] = A[M,K] . B[N,K]^T (+ biasM[m]) (+ biasN[n])
// ---------------------------------------------------------------------------
__global__ __launch_bounds__(256) void gemm_nt(const float* __restrict__ A,
                                               const float* __restrict__ B,
                                               const float* __restrict__ biasM,
                                               const float* __restrict__ biasN,
                                               float* __restrict__ C,
                                               int M, int N, int K) {
  __shared__ __align__(16) float At[32][68];
  __shared__ __align__(16) float Bt[32][68];
  const int t = threadIdx.x;
  const int m0 = blockIdx.x << 6, n0 = blockIdx.y << 6;
  const int r0 = t >> 3, c4 = (t & 7) << 2;
  const int tm = (t >> 4) << 2, tn = (t & 15) << 2;
  float acc[4][4];
#pragma unroll
  for (int i = 0; i < 4; ++i)
#pragma unroll
    for (int j = 0; j < 4; ++j) acc[i][j] = 0.f;

  for (int k0 = 0; k0 < K; k0 += 32) {
    float4 a0 = *(const float4*)&A[(size_t)(m0 + r0) * K + k0 + c4];
    float4 a1 = *(const float4*)&A[(size_t)(m0 + r0 + 32) * K + k0 + c4];
    float4 b0 = *(const float4*)&B[(size_t)(n0 + r0) * K + k0 + c4];
    float4 b1 = *(const float4*)&B[(size_t)(n0 + r0 + 32) * K + k0 + c4];
    __syncthreads();
    At[c4 + 0][r0] = a0.x; At[c4 + 1][r0] = a0.y; At[c4 + 2][r0] = a0.z; At[c4 + 3][r0] = a0.w;
    At[c4 + 0][r0 + 32] = a1.x; At[c4 + 1][r0 + 32] = a1.y; At[c4 + 2][r0 + 32] = a1.z; At[c4 + 3][r0 + 32] = a1.w;
    Bt[c4 + 0][r0] = b0.x; Bt[c4 + 1][r0] = b0.y; Bt[c4 + 2][r0] = b0.z; Bt[c4 + 3][r0] = b0.w;
    Bt[c4 + 0][r0 + 32] = b1.x; Bt[c4 + 1][r0 + 32] = b1.y; Bt[c4 + 2][r0 + 32] = b1.z; Bt[c4 + 3][r0 + 32] = b1.w;
    __syncthreads();
#pragma unroll
    for (int k = 0; k < 32; ++k) {
      float4 av = *(const float4*)&At[k][tm];
      float4 bv = *(const float4*)&Bt[k][tn];
      acc[0][0] = fmaf(av.x, bv.x, acc[0][0]);
      acc[0][1] = fmaf(av.x, bv.y, acc[0][1]);
      acc[0][2] = fmaf(av.x, bv.z, acc[0][2]);
      acc[0][3] = fmaf(av.x, bv.w, acc[0][3]);
      acc[1][0] = fmaf(av.y, bv.x, acc[1][0]);
      acc[1][1] = fmaf(av.y, bv.y, acc[1][1]);
      acc[1][2] = fmaf(av.y, bv.z, acc[1][2]);
      acc[1][3] = fmaf(av.y, bv.w, acc[1][3]);
      acc[2][0] = fmaf(av.z, bv.x, acc[2][0]);
      acc[2][1] = fmaf(av.z, bv.y, acc[2][1]);
      acc[2][2] = fmaf(av.z, bv.z, acc[2][2]);
      acc[2][3] = fmaf(av.z, bv.w, acc[2][3]);
      acc[3][0] = fmaf(av.w, bv.x, acc[3][0]);
      acc[3][1] = fmaf(av.w, bv.y, acc[3][1]);
      acc[3][2] = fmaf(av.w, bv.z, acc[3][2]);
      acc[3][3] = fmaf(av.w, bv.w, acc[3][3]);
    }
  }
#pragma unroll
  for (int i = 0; i < 4; ++i) {
    float bm = biasM ? biasM[m0 + tm + i] : 0.f;
#pragma unroll
    for (int j = 0; j < 4; ++j) {
      float bn = biasN ? biasN[n0 + tn + j] : 0.f;
      C[(size_t)(m0 + tm + i) * N + n0 + tn + j] = acc[i][j] + bm + bn;
    }
  }
}

// ---------------------------------------------------------------------------
// Persistent recurrence kernel — R7 tagged-dataflow (NB=128 x NT=512).
// FINAL configuration: the 15-round verified optimum (14.90 ms, reproduced
// twice). All dead experimental machinery removed.
//
// hb: compact uint32[2][2048]; slot = (16-bit epoch tag << 16 | fp16 h bits).
// Reader of step s polls buffer s&1 for tag s+1 (one dwordx4 sc0 sc1 covers
// its 4 slots). Producer at step s publishes tag s+2 into buffer (s+1)&1 via
// relaxed agent store. Init: owner block writes tag 1 to its 16 slots. Tags
// +1-offset; max tag 4097 < 2^16.
//
// Session ledger (why this exact shape):
//  - NB=128 is the block-count optimum: 256->18.55ms, 128->14.90ms; NB=64 is
//    architecturally closed (weights exceed the 256-addressable-VGPR VALU
//    limit -> spill [R11]; 8/16-wave blocks cap at 128/64 VGPR [R8/R9]).
//  - Poller count per block: null (R10). Traffic volume/layout/publish/
//    detect mechanism/pipelining: null or regress (R1-R6).
//  - Early-exit via limit-cycle detection: dynamics never lock (fp32 bitwise
//    [R13] nor fp16 broadcast [R14]) — slow drift at z~1 rows.
//  - Floor: 4096 inherently serial broadcast rounds x ~3.64us coherence-
//    point round-trip. Not memory-bound (HBM 0.55%) nor compute-bound
//    (VALU 12%) — latency-bound by the dependency chain itself.
//
// Buffer-reuse safety: a producer writes epoch e+2 only after polling ALL of
// e+1, which requires every block to have fully read epoch e (each block's
// tag-(e+1) publish sits after its barrier-synchronized staging of epoch e).
// ---------------------------------------------------------------------------
__global__ __launch_bounds__(NT) void recur_kernel(
    const float* __restrict__ giT_enc, const float* __restrict__ giT_dec,
    const float* __restrict__ enc_w_hh, const float* __restrict__ enc_b_hh,
    const float* __restrict__ dec_w_hh, const float* __restrict__ dec_b_hh,
    const int* __restrict__ inputs, const int* __restrict__ targets,
    unsigned int* __restrict__ hb, float* __restrict__ dec_hs) {
  __shared__ __align__(16) float gi_lds[48 * VV];       // 48 KB
  __shared__ __align__(16) _Float16 h16[2][Hh];         // 8 KB (double buffer)
  __shared__ __align__(16) unsigned short tok_lds[SS];  // 4 KB
  __shared__ float gidec_lds[96];

  const int t = threadIdx.x;
  const int b = blockIdx.x;
  const int bks = b << 4;  // 16 rows per block
  const int w = t >> 6, l = t & 63;
  const int ri = (w << 1) + (l & 1);  // this lane's epilogue row (in-block)

  // ---- recurrent weights + biases: two rows per wave, all in registers
  h4 wregA[24], wregB[24];
  float br_, bz_, bn_;
  auto load_wb = [&](const float* W, const float* B) {
#pragma unroll
    for (int g = 0; g < 3; ++g) {
      const float* r0 = W + ((size_t)(g * Hh + bks + (w << 1) + 0)) * Hh + (l << 2);
      const float* r1 = W + ((size_t)(g * Hh + bks + (w << 1) + 1)) * Hh + (l << 2);
#pragma unroll
      for (int q = 0; q < 8; ++q) {
        float4 v0 = *(const float4*)&r0[q * 256];
        float4 v1 = *(const float4*)&r1[q * 256];
        wregA[g * 8 + q] = h4{(_Float16)v0.x, (_Float16)v0.y,
                             (_Float16)v0.z, (_Float16)v0.w};
        wregB[g * 8 + q] = h4{(_Float16)v1.x, (_Float16)v1.y,
                             (_Float16)v1.z, (_Float16)v1.w};
      }
    }
    br_ = B[bks + ri];
    bz_ = B[Hh + bks + ri];
    bn_ = B[2 * Hh + bks + ri];
  };
  load_wb(enc_w_hh, enc_b_hh);

  // ---- stage encoder per-vocab input-gate slice: gi_lds[(g*16+rr)*256 + v]
  for (int r = 0; r < 48; ++r) {
    const int g = r >> 4, rr = r & 15;
    const float4* src = (const float4*)(giT_enc + ((size_t)(g * Hh + bks + rr)) * VV);
    if (t < 64) ((float4*)&gi_lds[r * VV])[t] = src[t];
  }

  // ---- tokens
  for (int u = t; u < SS; u += NT) tok_lds[u] = (unsigned short)inputs[u];

  // ---- decoder input-gates: only tokens {0, targets[1]}
  if (t < 96) {
    const int sel = t / 48, r48 = t % 48;
    const int tk = sel ? targets[1] : 0;
    const int g = r48 >> 4, rr = r48 & 15;
    gidec_lds[sel * 48 + r48] = giT_dec[((size_t)(g * Hh + bks + rr)) * VV + tk];
  }

  // ---- init own h slots: fp16 0.0 (bits 0), tag 1 (buffer 0)
  if (t < 16) {
    __hip_atomic_store(&hb[bks + t], 0x00010000u, __ATOMIC_RELAXED,
                       __HIP_MEMORY_SCOPE_AGENT);
  }
  float hprev = 0.0f;  // lanes 0/1 of wave w: running fp32 h[bks+2w+l]

  for (int step = 0; step < SS + TT; ++step) {
    if (step == SS) load_wb(dec_w_hh, dec_b_hh);  // private regs: no hazard
    const int sb = step & 1;

    // ---- poll the 4 tagged 32-bit slots this thread stages (one dwordx4)
    {
      const unsigned int* addr = hb + ((size_t)sb << 11) + (t << 2);
      const unsigned int want = ((unsigned int)(step + 1)) << 16;
      u32x4 v;
      for (;;) {
        asm volatile(
            "global_load_dwordx4 %0, %1, off sc0 sc1\n\t"
            "s_waitcnt vmcnt(0)"
            : "=&v"(v)
            : "v"(addr)
            : "memory");
        if ((v.x & 0xFFFF0000u) == want && (v.y & 0xFFFF0000u) == want &&
            (v.z & 0xFFFF0000u) == want && (v.w & 0xFFFF0000u) == want)
          break;
        __builtin_amdgcn_s_sleep(1);
      }
      u16x4 hu = {(unsigned short)v.x, (unsigned short)v.y,
                  (unsigned short)v.z, (unsigned short)v.w};
      *(u16x4*)&h16[sb][t << 2] = hu;
    }
    __syncthreads();

    // ---- six gate-row dot products (2 rows x 3 gates), fp16 dot2, fp32 acc
    float arA = 0.f, azA = 0.f, anA = 0.f;
    float arB = 0.f, azB = 0.f, anB = 0.f;
#pragma unroll
    for (int q = 0; q < 8; ++q) {
      const int c = q * 256 + (l << 2);
      h4 hv = *(const h4*)&h16[sb][c];
      h2 hlo = SH(hv, 0, 1);
      h2 hhi = SH(hv, 2, 3);
      h4 a_r = wregA[q], a_z = wregA[8 + q], a_n = wregA[16 + q];
      h4 b_r = wregB[q], b_z = wregB[8 + q], b_n = wregB[16 + q];
      arA = FDOT2(SH(a_r, 0, 1), hlo, arA); arA = FDOT2(SH(a_r, 2, 3), hhi, arA);
      azA = FDOT2(SH(a_z, 0, 1), hlo, azA); azA = FDOT2(SH(a_z, 2, 3), hhi, azA);
      anA = FDOT2(SH(a_n, 0, 1), hlo, anA); anA = FDOT2(SH(a_n, 2, 3), hhi, anA);
      arB = FDOT2(SH(b_r, 0, 1), hlo, arB); arB = FDOT2(SH(b_r, 2, 3), hhi, arB);
      azB = FDOT2(SH(b_z, 0, 1), hlo, azB); azB = FDOT2(SH(b_z, 2, 3), hhi, azB);
      anB = FDOT2(SH(b_n, 0, 1), hlo, anB); anB = FDOT2(SH(b_n, 2, 3), hhi, anB);
    }

    // ---- gate inputs hoisted above the reduce (row-matched via ri)
    float gr, gz, gn;
    if (step < SS) {
      const int tk = tok_lds[step];
      gr = gi_lds[(0 + ri) * VV + tk];
      gz = gi_lds[(16 + ri) * VV + tk];
      gn = gi_lds[(32 + ri) * VV + tk];
    } else {
      const int sel = (step == SS) ? 0 : 48;
      gr = gidec_lds[sel + 0 + ri];
      gz = gidec_lds[sel + 16 + ri];
      gn = gidec_lds[sel + 32 + ri];
    }

#pragma unroll
    for (int off = 32; off > 0; off >>= 1) {
      arA += __shfl_xor(arA, off); azA += __shfl_xor(azA, off); anA += __shfl_xor(anA, off);
      arB += __shfl_xor(arB, off); azB += __shfl_xor(azB, off); anB += __shfl_xor(anB, off);
    }

    if (l < 2) {  // lane 0 -> row bks+2w, lane 1 -> row bks+2w+1
      const float ar = l ? arB : arA;
      const float az = l ? azB : azA;
      const float an = l ? anB : anA;
      const float xr = gr + ar + br_;
      const float xz = gz + az + bz_;
      const float hn = an + bn_;
      const float rr = 1.f / (1.f + __expf(-xr));
      const float zz = 1.f / (1.f + __expf(-xz));
      const float nn = tanhf(gn + rr * hn);
      const float hnew = (1.f - zz) * nn + zz * hprev;

      _Float16 hf = (_Float16)hnew;
      const unsigned int pk =
          (((unsigned int)(step + 2)) << 16) |
          (unsigned int)__builtin_bit_cast(unsigned short, hf);
      __hip_atomic_store(&hb[(((size_t)((step + 1) & 1)) << 11) + bks + ri], pk,
                         __ATOMIC_RELAXED, __HIP_MEMORY_SCOPE_AGENT);
      if (step >= SS) dec_hs[(size_t)(step - SS) * Hh + bks + ri] = hnew;
      hprev = hnew;
    }
    // no trailing barrier: h16 is double-buffered; weights/biases are private
  }
}

// ---------------------------------------------------------------------------
extern "C" void kernel_launch(void* const* d_in, const int* in_sizes, int n_in,
                              void* d_out, int out_size, void* d_ws, size_t ws_size,
                              hipStream_t stream) {
  (void)in_sizes; (void)n_in; (void)out_size; (void)ws_size;
  const int* inputs = (const int*)d_in[0];
  const int* targets = (const int*)d_in[1];
  const float* emb = (const float*)d_in[2];
  const float* enc_w_ih = (const float*)d_in[3];
  const float* enc_w_hh = (const float*)d_in[4];
  const float* enc_b_ih = (const float*)d_in[5];
  const float* enc_b_hh = (const float*)d_in[6];
  const float* dec_w_ih = (const float*)d_in[7];
  const float* dec_w_hh = (const float*)d_in[8];
  const float* dec_b_ih = (const float*)d_in[9];
  const float* dec_b_hh = (const float*)d_in[10];
  const float* fc_w = (const float*)d_in[11];
  const float* fc_b = (const float*)d_in[12];
  float* out = (float*)d_out;

  // workspace layout
  float* giT_enc = (float*)d_ws;                          // [6144][256]
  float* giT_dec = giT_enc + (size_t)6144 * 256;          // [6144][256]
  float* dec_hs = giT_dec + (size_t)6144 * 256;           // [2048][2048]
  unsigned int* hb =
      (unsigned int*)(dec_hs + (size_t)TT * Hh);          // [2][2048] tagged u32

  // per-vocab input-gate tables: giT[r][v] = W_ih[r] . emb[v] + b_ih[r]
  gemm_nt<<<dim3(96, 4), 256, 0, stream>>>(enc_w_ih, emb, enc_b_ih, nullptr,
                                           giT_enc, 3 * Hh, VV, Hh);
  gemm_nt<<<dim3(96, 4), 256, 0, stream>>>(dec_w_ih, emb, dec_b_ih, nullptr,
                                           giT_dec, 3 * Hh, VV, Hh);

  void* args[] = {&giT_enc, &giT_dec, &enc_w_hh, &enc_b_hh, &dec_w_hh,
                  &dec_b_hh, &inputs, &targets, &hb, &dec_hs};
  hipError_t e = hipLaunchCooperativeKernel((void*)recur_kernel, dim3(NB),
                                            dim3(NT), args, 0, stream);
  if (e != hipSuccess) {
    recur_kernel<<<dim3(NB), dim3(NT), 0, stream>>>(
        giT_enc, giT_dec, enc_w_hh, enc_b_hh, dec_w_hh, dec_b_hh, inputs,
        targets, hb, dec_hs);
  }

  // out[t][v] = dec_hs[t] . fc_w[v] + fc_b[v]
  gemm_nt<<<dim3(32, 4), 256, 0, stream>>>(dec_hs, fc_w, nullptr, fc_b, out,
                                           TT, VV, Hh);
}